// Round 3
// baseline (183.067 us; speedup 1.0000x reference)
//
#include <hip/hip_runtime.h>

#define BINS  30
#define NROWS 8192
#define NCOLS 2048
#define COLS_PER_BLK 256                 // grid.x = 8
#define ROWS_PER_BLK 128                 // grid.y = 64
#define YSLICES 64

#define FIXED_SCALE 16384.0f             // 2^14 fixed point for bce
#define CNT_SHIFT   24                   // count bit 24, sum in [0:24)
#define SUM_MASK    ((1u << CNT_SHIFT) - 1)

// ws layout (bytes):
//   part : u32[YSLICES][BINS][NCOLS]   (15.7 MB)
//   cnt  : float[BINS][NCOLS]          (245760 B)
//   bsum : float[BINS][NCOLS]          (245760 B)
//   blockPart: float[8]
//   ctr  : u32 (last-block-done counter)
#define WS_PART  0
#define WS_CNT   (YSLICES * BINS * NCOLS * 4)
#define WS_BSUM  (WS_CNT + BINS * NCOLS * 4)
#define WS_BPART (WS_BSUM + BINS * NCOLS * 4)
#define WS_CTR   (WS_BPART + 8 * 4)

// ---------------------------------------------------------------------------
// Kernel A (R3): DIRECT COLUMN OWNERSHIP — no atomics, no barriers, no staging.
// Post-mortem R1/R2: HBM-scatter and LDS-atomic theories both falsified;
// kernel is concurrency-bound (VALU busy-time ~16us of 51us wall; R2's
// barrier-lockstep at 4 waves/SIMD can't cover trans+DS+load latency).
// R3: thread t owns column colBase+t outright:
//   - loads: 64 lanes x dword = 256B contiguous per row -> fully coalesced
//   - H[b*256+t] += pk : exclusive by construction (unique t per thread),
//     plain DS RMW, 2 ds-ops/element (vs R2's 4), bank = t%32 -> 2-way free
//   - ZERO __syncthreads in the hot loop; waves free-run
// LDS = 30720 B only -> 5 blocks/CU = 20 waves/CU (launch_bounds(256,5),
// VGPR cap 102). Batch-8 rows with depth-1 prefetch pinned by
// sched_barrier(0). Integer adds exact in any order -> part[] bit-identical.
// ---------------------------------------------------------------------------
__global__ __launch_bounds__(256, 5) void k_main(
    const float* __restrict__ preds, const int* __restrict__ targets,
    unsigned int* __restrict__ part, unsigned int* __restrict__ ctr)
{
    __shared__ unsigned int H[BINS * COLS_PER_BLK];   // 30720 B
    const int t = threadIdx.x;
    if (blockIdx.x == 0 && blockIdx.y == 0 && t == 0) atomicExch(ctr, 0u);
    #pragma unroll
    for (int i = 0; i < BINS; ++i) H[i * COLS_PER_BLK + t] = 0u;
    __syncthreads();

    const int col = blockIdx.x * COLS_PER_BLK + t;
    const int r0  = blockIdx.y * ROWS_PER_BLK;
    const float* P = preds   + (size_t)r0 * NCOLS + col;
    const int*   T = targets + (size_t)r0 * NCOLS + col;

    // prologue: batch 0 (8 rows) in flight
    float pc[8]; int tc[8];
    #pragma unroll
    for (int r = 0; r < 8; ++r) { pc[r] = P[r * NCOLS]; tc[r] = T[r * NCOLS]; }

    #pragma unroll 1
    for (int batch = 0; batch < ROWS_PER_BLK / 8; ++batch) {
        float pn[8]; int tn[8];
        if (batch < ROWS_PER_BLK / 8 - 1) {
            P += 8 * NCOLS; T += 8 * NCOLS;
            #pragma unroll
            for (int r = 0; r < 8; ++r) { pn[r] = P[r * NCOLS]; tn[r] = T[r * NCOLS]; }
        }
        __builtin_amdgcn_sched_barrier(0);   // prefetch loads may not sink

        #pragma unroll
        for (int r = 0; r < 8; ++r) {
            float p  = pc[r];
            float pp = tc[r] ? -p : p;                    // p'
            float e  = __expf(-fabsf(pp));                // exp(-|p'|)
            float d  = 1.0f + e;
            float r1 = __builtin_amdgcn_rcpf(d);
            float g  = (pp >= 0.0f) ? r1 : e * r1;        // sigmoid(p')
            int   b  = (int)(g * 30.0f);
            b = b > (BINS - 1) ? (BINS - 1) : b;
            float bce = fmaxf(pp, 0.0f) + __logf(d);      // softplus(p')
            unsigned int pk = (1u << CNT_SHIFT)
                | (unsigned int)(bce * FIXED_SCALE + 0.5f);
            H[b * COLS_PER_BLK + t] += pk;                // exclusive, plain RMW
        }
        #pragma unroll
        for (int r = 0; r < 8; ++r) { pc[r] = pn[r]; tc[r] = tn[r]; }
    }
    __syncthreads();

    // flush: straight copy, coalesced
    const size_t outBase = (size_t)blockIdx.y * BINS * NCOLS
                         + (size_t)blockIdx.x * COLS_PER_BLK;
    for (int i = t; i < BINS * COLS_PER_BLK; i += 256)
        part[outBase + (size_t)(i >> 8) * NCOLS + (i & 255)] = H[i];
}

// ---------------------------------------------------------------------------
// Kernel B: wide y-slice reduction with unpack (unchanged).
// ---------------------------------------------------------------------------
__global__ __launch_bounds__(256) void k_reduce(
    const unsigned int* __restrict__ part,
    float* __restrict__ cnt_f, float* __restrict__ bsum_f)
{
    const int id = blockIdx.x * 256 + threadIdx.x;    // 0 .. 61439
    unsigned int cnt = 0u, sm = 0u;
    #pragma unroll 16
    for (int y = 0; y < YSLICES; ++y) {
        const unsigned int v = part[(size_t)y * BINS * NCOLS + id];
        cnt += v >> CNT_SHIFT;
        sm  += v & SUM_MASK;
    }
    cnt_f[id]  = (float)cnt;
    bsum_f[id] = (float)sm * (1.0f / FIXED_SCALE);
}

// ---------------------------------------------------------------------------
// Kernel C: per-column contraction + fused final sum (unchanged from R2).
// ---------------------------------------------------------------------------
__global__ __launch_bounds__(256) void k_colsum(
    const float* __restrict__ cnt_f, const float* __restrict__ bsum_f,
    const float* __restrict__ acc_sum, float* __restrict__ blockPart,
    unsigned int* __restrict__ ctr, float* __restrict__ out)
{
    __shared__ float wave_sums[4];
    const int tid = threadIdx.x;
    const int c   = blockIdx.x * 256 + tid;

    float colsum = 0.0f;
    int n = 0;
    #pragma unroll
    for (int b = 0; b < BINS; ++b) {
        const size_t gidx = (size_t)b * NCOLS + c;
        const float cnt = cnt_f[gidx];
        if (cnt >= 1.0f) {
            n += 1;
            float acc_new = 0.75f * acc_sum[gidx] + 0.25f * cnt;
            colsum += bsum_f[gidx] / acc_new;
        }
    }
    colsum /= (float)((n > 1 ? n : 1) * NCOLS);

    #pragma unroll
    for (int off = 32; off > 0; off >>= 1)
        colsum += __shfl_down(colsum, off, 64);
    if ((tid & 63) == 0) wave_sums[tid >> 6] = colsum;
    __syncthreads();
    if (tid == 0) {
        const float s = wave_sums[0] + wave_sums[1] + wave_sums[2] + wave_sums[3];
        atomicExch(&blockPart[blockIdx.x], s);    // coherent publish
        __threadfence();
        if (atomicAdd(ctr, 1u) == 7u) {           // last block finishes
            __threadfence();
            double d = 0.0;
            #pragma unroll
            for (int i = 0; i < 8; ++i)
                d += (double)atomicAdd(&blockPart[i], 0.0f);  // coherent fetch
            out[0] = (float)d;
        }
    }
}

extern "C" void kernel_launch(void* const* d_in, const int* in_sizes, int n_in,
                              void* d_out, int out_size, void* d_ws, size_t ws_size,
                              hipStream_t stream)
{
    const float* preds   = (const float*)d_in[0];
    const int*   targets = (const int*)d_in[1];
    const float* acc_sum = (const float*)d_in[2];

    unsigned int* part = (unsigned int*)((char*)d_ws + WS_PART);
    float* cnt_f       = (float*)((char*)d_ws + WS_CNT);
    float* bsum_f      = (float*)((char*)d_ws + WS_BSUM);
    float* blockPart   = (float*)((char*)d_ws + WS_BPART);
    unsigned int* ctr  = (unsigned int*)((char*)d_ws + WS_CTR);

    dim3 gA(NCOLS / COLS_PER_BLK, NROWS / ROWS_PER_BLK);   // (8, 64) = 512 blocks
    k_main<<<gA, 256, 0, stream>>>(preds, targets, part, ctr);

    k_reduce<<<(BINS * NCOLS) / 256, 256, 0, stream>>>(part, cnt_f, bsum_f);

    k_colsum<<<NCOLS / 256, 256, 0, stream>>>(cnt_f, bsum_f, acc_sum,
                                              blockPart, ctr, (float*)d_out);
}